// Round 1
// 539.403 us; speedup vs baseline: 1.0112x; 1.0112x over previous
//
#include <hip/hip_runtime.h>
#include <hip/hip_bf16.h>

// AutoregressiveResidualBlock — Round 3: gemm1 ported to the verified
// 256x256 8-phase template (T1 XCD swizzle + T2 LDS XOR swizzle + T3/T4
// counted vmcnt phases + T5 setprio). gemm2 (N=512 -> only 128 tiles at
// 256^2) stays on the known-good m97 128^2 kernel. prep unchanged.
//
// Layout (K-permutation; GEMM invariant under shared K-perm of A and B):
//   A2[b][k] (bf16, stride 3072): [q2 | h1 | q1 | x] blocks of 1024/1024/512/512
//   w1p[m][1024] = [w1 even cols | w1 odd cols]
//   w2p[o][3072] = [w2 even | w2 odd | wsk even | wsk odd]
// gemm1: A=A2[:,2048:] (K=1024) x w1p -> h1=bn1(relu(.+b1)) into A2[:,1024:2048]
// gemm2: A=A2 (K=3072) x w2p -> out=bn2(relu(.+b2+bsk))  (skip folded into K)

#define BS   16384
#define DIN  512
#define MID  1024
#define NOUT 512
#define KA2  3072
#define BN_EPS 1e-5f

typedef __attribute__((ext_vector_type(8))) short bf16x8;
typedef __attribute__((ext_vector_type(4))) float floatx4;

#define GLDS(g, l) __builtin_amdgcn_global_load_lds( \
    (const __attribute__((address_space(1))) void*)(g), \
    (__attribute__((address_space(3))) void*)(l), 16, 0, 0)

__device__ __forceinline__ void cvt_store8(const float* __restrict__ src,
                                           __hip_bfloat16* __restrict__ dst) {
    float4 u = *(const float4*)src;
    float4 v = *(const float4*)(src + 4);
    __hip_bfloat16 tmp[8] __attribute__((aligned(16)));
    tmp[0] = __float2bfloat16(u.x); tmp[1] = __float2bfloat16(u.y);
    tmp[2] = __float2bfloat16(u.z); tmp[3] = __float2bfloat16(u.w);
    tmp[4] = __float2bfloat16(v.x); tmp[5] = __float2bfloat16(v.y);
    tmp[6] = __float2bfloat16(v.z); tmp[7] = __float2bfloat16(v.w);
    *(float4*)dst = *(const float4*)tmp;
}

// strided (every-other) fp32 -> 8 packed bf16
__device__ __forceinline__ void cvt_store8_s2(const float* __restrict__ src,
                                              __hip_bfloat16* __restrict__ dst) {
    __hip_bfloat16 tmp[8] __attribute__((aligned(16)));
#pragma unroll
    for (int i = 0; i < 8; ++i) tmp[i] = __float2bfloat16(src[2 * i]);
    *(float4*)dst = *(const float4*)tmp;
}

#define T_Q2  ((long)BS * 128)          // 2,097,152 threads: q2 -> A2[:,0:1024]
#define T_Q1X ((long)BS * 64)           // 1,048,576: q1 -> A2[:,2048:2560], x -> [:,2560:3072]
#define T_W1  (1024L * 1024 / 8)        //   131,072: w1 -> w1p
#define T_W2  (512L * 3072 / 8)         //   196,608: w2/wsk -> w2p
#define T_ALL (T_Q2 + T_Q1X + T_W1 + T_W2)   // 3,473,408 = 13568 * 256

__global__ __launch_bounds__(256) void prep_all_kernel(
    const float* __restrict__ x, const float* __restrict__ q1,
    const float* __restrict__ q2, const float* __restrict__ w1,
    const float* __restrict__ w2, const float* __restrict__ wsk,
    __hip_bfloat16* __restrict__ A2,
    __hip_bfloat16* __restrict__ w1p, __hip_bfloat16* __restrict__ w2p)
{
    long id = (long)blockIdx.x * 256 + threadIdx.x;
    if (id < T_Q2) {
        long b = id >> 7;
        int j = (int)(id & 127) << 3;
        cvt_store8(q2 + b * MID + j, A2 + b * KA2 + j);
    } else if (id < T_Q2 + T_Q1X) {
        long id2 = id - T_Q2;
        long b = id2 >> 6;
        int j = (int)(id2 & 63) << 3;
        cvt_store8(q1 + b * DIN + j, A2 + b * KA2 + 2048 + j);
        cvt_store8(x  + b * DIN + j, A2 + b * KA2 + 2560 + j);
    } else if (id < T_Q2 + T_Q1X + T_W1) {
        long t = id - (T_Q2 + T_Q1X);
        long o8 = t * 8;                       // output index in w1p
        int m = (int)(o8 >> 10), k0 = (int)(o8 & 1023);
        const float* src = w1 + m * 1024 + ((k0 < 512) ? 2 * k0 : 2 * (k0 - 512) + 1);
        cvt_store8_s2(src, w1p + o8);
    } else {
        long t = id - (T_Q2 + T_Q1X + T_W1);
        long o8 = t * 8;                       // output index in w2p
        int o = (int)(o8 / 3072), k0 = (int)(o8 - (long)o * 3072);
        const float* src;
        if (k0 < 1024)      src = w2 + o * 2048 + 2 * k0;
        else if (k0 < 2048) src = w2 + o * 2048 + 2 * (k0 - 1024) + 1;
        else if (k0 < 2560) src = wsk + o * 1024 + 2 * (k0 - 2048);
        else                src = wsk + o * 1024 + 2 * (k0 - 2560) + 1;
        cvt_store8_s2(src, w2p + o8);
    }
}

// ---------------------------------------------------------------------------
// gemm1: 256x256 tile, BK=64, 512 threads (8 waves = 2M x 4N), 8-phase
// schedule with counted vmcnt, raw s_barrier (no vmcnt(0) drain), LDS XOR
// swizzle (chunk ^= row&7, 16B granularity) applied on BOTH the pre-swizzled
// global_load_lds source and the ds_read address (conflict-free at 128B rows).
// M=16384, N=1024, K=1024 -> grid 64x4 = 256 blocks = 1 block/CU.
// ---------------------------------------------------------------------------

#define PBAR() do { __builtin_amdgcn_sched_barrier(0); \
                    __builtin_amdgcn_s_barrier(); \
                    __builtin_amdgcn_sched_barrier(0); } while (0)
#define LGKM0() asm volatile("s_waitcnt lgkmcnt(0)" ::: "memory")
#define VMW(n)  asm volatile("s_waitcnt vmcnt(" #n ")" ::: "memory")

// stage a full 256x64 bf16 K-tile (A or B operand) into LDS buf.
// phys chunk f = row*8 + cc holds logical chunk (row, cc ^ (row&7)):
// linear LDS dest (global_load_lds requirement) + inverse-swizzled source.
#define STAGE_TILE(G, STRIDE, ROWBLK, K0, LBASE) do { \
    _Pragma("unroll") for (int c_ = 0; c_ < 4; ++c_) { \
        int f0_ = (c_ * 8 + wave) * 64; \
        int f_  = f0_ + lane; \
        int sr_ = f_ >> 3, cc_ = f_ & 7; \
        GLDS((G) + (size_t)((ROWBLK) + sr_) * (STRIDE) + (K0) + ((cc_ ^ (sr_ & 7)) << 3), \
             ((short*)(LBASE)) + f0_ * 8); \
    } } while (0)

// read one i-half (4 M-frags x 2 k-slices) of this wave's A rows
#define READ_A(BUF, IH) do { \
    _Pragma("unroll") for (int i_ = 0; i_ < 4; ++i_) { \
        int r_ = wm * 128 + (IH) * 64 + i_ * 16 + (lane & 15); \
        _Pragma("unroll") for (int kk_ = 0; kk_ < 2; ++kk_) { \
            int cc_ = (kk_ * 4 + (lane >> 4)) ^ (r_ & 7); \
            a[i_][kk_] = *(const bf16x8*)&As[BUF][r_][cc_ * 8]; \
        } } } while (0)

// read one j-half (2 N-frags x 2 k-slices) of this wave's B rows
#define READ_B(BUF, JH) do { \
    _Pragma("unroll") for (int j_ = 0; j_ < 2; ++j_) { \
        int r_ = wn * 64 + (JH) * 32 + j_ * 16 + (lane & 15); \
        _Pragma("unroll") for (int kk_ = 0; kk_ < 2; ++kk_) { \
            int cc_ = (kk_ * 4 + (lane >> 4)) ^ (r_ & 7); \
            b[(JH) * 2 + j_][kk_] = *(const bf16x8*)&Bs[BUF][r_][cc_ * 8]; \
        } } } while (0)

// one C-quadrant: 4 i x 2 j x 2 kk = 16 MFMA, setprio-wrapped (T5)
#define MFMA_Q(IH, JH) do { \
    __builtin_amdgcn_s_setprio(1); \
    _Pragma("unroll") for (int i_ = 0; i_ < 4; ++i_) \
    _Pragma("unroll") for (int j_ = 0; j_ < 2; ++j_) \
    _Pragma("unroll") for (int kk_ = 0; kk_ < 2; ++kk_) \
        acc[(IH) * 4 + i_][(JH) * 2 + j_] = __builtin_amdgcn_mfma_f32_16x16x32_bf16( \
            a[i_][kk_], b[(JH) * 2 + j_][kk_], acc[(IH) * 4 + i_][(JH) * 2 + j_], 0, 0, 0); \
    __builtin_amdgcn_s_setprio(0); \
} while (0)

__global__ __launch_bounds__(512, 2) void gemm1_8ph(
    const __hip_bfloat16* __restrict__ Ag,   // A2 + 2048, row stride KA2
    const __hip_bfloat16* __restrict__ Bg,   // w1p, row stride 1024
    const float* __restrict__ bias,
    const float* __restrict__ bn_s, const float* __restrict__ bn_b,
    const float* __restrict__ bn_m, const float* __restrict__ bn_v,
    __hip_bfloat16* __restrict__ hout)       // A2 + 1024, row stride KA2
{
    __shared__ __align__(16) short As[2][256][64];   // 64 KiB
    __shared__ __align__(16) short Bs[2][256][64];   // 64 KiB

    const int t = threadIdx.x;
    const int lane = t & 63;
    const int wave = t >> 6;        // 0..7
    const int wm = wave >> 2;       // 0..1 : wave row  (128 rows each)
    const int wn = wave & 3;        // 0..3 : wave col  (64 cols each)

    // T1: grid 256 = 64 Mblk x 4 Nblk; all 4 N-blocks of an M-strip share
    // (p&7) -> same XCD -> A-strip L2 locality. 256 % 8 == 0 -> bijective.
    const int p = blockIdx.x;
    const int m0 = ((p & 7) + 8 * ((p >> 3) & 7)) * 256;
    const int n0 = (p >> 6) * 256;

    floatx4 acc[8][4];
#pragma unroll
    for (int i = 0; i < 8; ++i)
#pragma unroll
        for (int j = 0; j < 4; ++j)
            acc[i][j] = (floatx4){0.f, 0.f, 0.f, 0.f};

    bf16x8 a[4][2], b[4][2];

    // prologue: stage K-tiles 0 (buf0) and 1 (buf1), full drain once.
    STAGE_TILE(Bg, 1024, n0, 0,  Bs[0]);
    STAGE_TILE(Ag, KA2,  m0, 0,  As[0]);
    STAGE_TILE(Bg, 1024, n0, 64, Bs[1]);
    STAGE_TILE(Ag, KA2,  m0, 64, As[1]);
    VMW(0);
    __builtin_amdgcn_s_barrier();

    // main loop: iteration it consumes K-tiles (2it, 2it+1) from (buf0,buf1)
    // and stages K-tiles (2it+2 -> buf0 at P3/P4, 2it+3 -> buf1 at P7/P8).
    // vmcnt(4) at P4/P8 allows exactly one staged tile (4 loads) in flight.
    for (int it = 0; it < 8; ++it) {
        const bool more = (it < 7);
        const int kn = it * 128 + 128;

        // ---- P1: Q(0,0)
        READ_A(0, 0); READ_B(0, 0);
        PBAR(); LGKM0(); MFMA_Q(0, 0); PBAR();
        // ---- P2: Q(0,1)
        READ_B(0, 1);
        PBAR(); LGKM0(); MFMA_Q(0, 1); PBAR();
        // ---- P3: Q(1,1)  + stage next B tile (buf0 B fully read at P2)
        READ_A(0, 1);
        if (more) STAGE_TILE(Bg, 1024, n0, kn, Bs[0]);
        PBAR(); LGKM0(); MFMA_Q(1, 1); PBAR();
        // ---- P4: Q(1,0)  + wait + stage next A tile (buf0 A read at P3)
        if (more) { VMW(4); } else { VMW(0); }   // final iter: drain for P5 reads
        if (more) STAGE_TILE(Ag, KA2, m0, kn, As[0]);
        PBAR(); MFMA_Q(1, 0); PBAR();

        // ---- P5: Q(0,0) on buf1
        READ_A(1, 0); READ_B(1, 0);
        PBAR(); LGKM0(); MFMA_Q(0, 0); PBAR();
        // ---- P6: Q(0,1)
        READ_B(1, 1);
        PBAR(); LGKM0(); MFMA_Q(0, 1); PBAR();
        // ---- P7: Q(1,1)  + stage next B tile (buf1)
        READ_A(1, 1);
        if (more) STAGE_TILE(Bg, 1024, n0, kn + 64, Bs[1]);
        PBAR(); LGKM0(); MFMA_Q(1, 1); PBAR();
        // ---- P8: Q(1,0)  + wait + stage next A tile (buf1)
        VMW(4);
        if (more) STAGE_TILE(Ag, KA2, m0, kn + 64, As[1]);
        PBAR(); MFMA_Q(1, 0); PBAR();
    }

    // epilogue: bn1(relu(+b1)) -> bf16 into A2[:,1024:2048]
#pragma unroll
    for (int j = 0; j < 4; ++j) {
        int col = n0 + wn * 64 + j * 16 + (lane & 15);
        float bias_v = bias[col];
        float scale = bn_s[col] * rsqrtf(bn_v[col] + BN_EPS);
        float mean = bn_m[col], beta = bn_b[col];
#pragma unroll
        for (int i = 0; i < 8; ++i) {
            int rbase = m0 + wm * 128 + i * 16 + (lane >> 4) * 4;
#pragma unroll
            for (int r = 0; r < 4; ++r) {
                float v = acc[i][j][r] + bias_v;
                v = fmaxf(v, 0.f);
                v = (v - mean) * scale + beta;
                hout[(size_t)(rbase + r) * KA2 + col] = __float2bfloat16(v);
            }
        }
    }
}

// ---------------------------------------------------------------------------
// m97-style 128x128 bf16 MFMA GEMM (kept for gemm2: N=512 only fills 128
// blocks at 256^2, so the 512-block 128^2 kernel wins on occupancy).
// EPI==2: bn2(relu(+a+b)) -> fp32 fout
// ---------------------------------------------------------------------------
template <int EPI>
__global__ __launch_bounds__(256) void mfma_gemm(
    const __hip_bfloat16* __restrict__ A, const __hip_bfloat16* __restrict__ B,
    int K, long strideA,
    const float* __restrict__ bias_a, const float* __restrict__ bias_b,
    const float* __restrict__ bn_s, const float* __restrict__ bn_b,
    const float* __restrict__ bn_m, const float* __restrict__ bn_v,
    __hip_bfloat16* __restrict__ hout, float* __restrict__ fout, int strideOut)
{
    __shared__ short Asl[128 * 32];
    __shared__ short Bsl[128 * 32];

    const int t = threadIdx.x;
    const int lane = t & 63;
    const int wave = t >> 6;
    const int wm = wave >> 1, wn = wave & 1;

    const int p = blockIdx.x;
    const int m0 = ((p & 7) + 8 * ((p >> 3) & 15)) * 128;
    const int n0 = ((p >> 3) >> 4) * 128;

    floatx4 acc[4][4];
#pragma unroll
    for (int i = 0; i < 4; ++i)
#pragma unroll
        for (int j = 0; j < 4; ++j)
            acc[i][j] = (floatx4){0.f, 0.f, 0.f, 0.f};

    for (int k0 = 0; k0 < K; k0 += 32) {
#pragma unroll
        for (int c = 0; c < 2; ++c) {
            int fb = c * 256 + wave * 64;   // wave-uniform
            int f = fb + lane;              // row=f>>2, 16B chunk=f&3
            GLDS(A + (size_t)(m0 + (f >> 2)) * strideA + k0 + (f & 3) * 8,
                 Asl + fb * 8);
            GLDS(B + (size_t)(n0 + (f >> 2)) * (size_t)K + k0 + (f & 3) * 8,
                 Bsl + fb * 8);
        }
        __syncthreads();

        bf16x8 af[4], bfr[4];
#pragma unroll
        for (int i = 0; i < 4; ++i)
            af[i] = *(const bf16x8*)&Asl[(wm * 64 + i * 16 + (lane & 15)) * 32 +
                                         (lane >> 4) * 8];
#pragma unroll
        for (int j = 0; j < 4; ++j)
            bfr[j] = *(const bf16x8*)&Bsl[(wn * 64 + j * 16 + (lane & 15)) * 32 +
                                          (lane >> 4) * 8];
#pragma unroll
        for (int i = 0; i < 4; ++i)
#pragma unroll
            for (int j = 0; j < 4; ++j)
                acc[i][j] = __builtin_amdgcn_mfma_f32_16x16x32_bf16(
                    af[i], bfr[j], acc[i][j], 0, 0, 0);
        __syncthreads();
    }

#pragma unroll
    for (int j = 0; j < 4; ++j) {
        int col = n0 + wn * 64 + j * 16 + (lane & 15);
        float bias = bias_a[col];
        if (EPI == 2) bias += bias_b[col];
        float scale = bn_s[col] * rsqrtf(bn_v[col] + BN_EPS);
        float mean = bn_m[col], beta = bn_b[col];
#pragma unroll
        for (int i = 0; i < 4; ++i) {
            int rbase = m0 + wm * 64 + i * 16 + (lane >> 4) * 4;
#pragma unroll
            for (int r = 0; r < 4; ++r) {
                float v = acc[i][j][r] + bias;
                v = fmaxf(v, 0.f);
                v = (v - mean) * scale + beta;
                if (EPI == 1)
                    hout[(size_t)(rbase + r) * strideOut + col] = __float2bfloat16(v);
                else
                    fout[(size_t)(rbase + r) * strideOut + col] = v;
            }
        }
    }
}

extern "C" void kernel_launch(void* const* d_in, const int* in_sizes, int n_in,
                              void* d_out, int out_size, void* d_ws, size_t ws_size,
                              hipStream_t stream) {
    const float* x   = (const float*)d_in[0];
    const float* q1  = (const float*)d_in[1];
    const float* q2  = (const float*)d_in[2];
    const float* w1  = (const float*)d_in[3];
    const float* b1  = (const float*)d_in[4];
    const float* w2  = (const float*)d_in[5];
    const float* b2  = (const float*)d_in[6];
    const float* wsk = (const float*)d_in[7];
    const float* bsk = (const float*)d_in[8];
    const float* s1  = (const float*)d_in[9];
    const float* bb1 = (const float*)d_in[10];
    const float* m1  = (const float*)d_in[11];
    const float* v1  = (const float*)d_in[12];
    const float* s2  = (const float*)d_in[13];
    const float* bb2 = (const float*)d_in[14];
    const float* m2  = (const float*)d_in[15];
    const float* v2  = (const float*)d_in[16];
    float* out = (float*)d_out;

    size_t needA2 = (size_t)BS * KA2 * sizeof(__hip_bfloat16);
    size_t needW  = ((size_t)1024 * 1024 + (size_t)512 * 3072) * sizeof(__hip_bfloat16);
    char* base;
    if (ws_size >= needA2 + needW)
        base = (char*)d_ws;
    else
        base = (char*)d_in[2] + (size_t)BS * MID * sizeof(float);
    __hip_bfloat16* A2  = (__hip_bfloat16*)base;
    __hip_bfloat16* w1p = (__hip_bfloat16*)(base + needA2);
    __hip_bfloat16* w2p = w1p + 1024 * 1024;

    prep_all_kernel<<<dim3((int)(T_ALL / 256)), dim3(256), 0, stream>>>(
        x, q1, q2, w1, w2, wsk, A2, w1p, w2p);

    // gemm1: M=16384, N=1024, K=1024; h1 -> A2[:,1024:2048]  (8-phase 256^2)
    gemm1_8ph<<<dim3(256), dim3(512), 0, stream>>>(
        A2 + 2048, w1p, b1, s1, bb1, m1, v1, A2 + 1024);

    // gemm2: M=16384, N=512, K=3072 (w2 + skip folded); out fp32
    mfma_gemm<2><<<dim3(512), dim3(256), 0, stream>>>(
        A2, w2p, 3072, KA2,
        b2, bsk, s2, bb2, m2, v2,
        nullptr, out, NOUT);
}

// Round 2
// 516.659 us; speedup vs baseline: 1.0557x; 1.0440x over previous
//
#include <hip/hip_runtime.h>
#include <hip/hip_bf16.h>

// AutoregressiveResidualBlock — Round 4: gemm2 ported to an 8-phase-style
// counted-vmcnt schedule with 256x128 tile (BM=256,BN=128,BK=64, 4 phases /
// 2 K-tiles per iteration). gemm1 keeps the verified 256^2 8-phase kernel.
// prep unchanged.
//
// Layout (K-permutation; GEMM invariant under shared K-perm of A and B):
//   A2[b][k] (bf16, stride 3072): [q2 | h1 | q1 | x] blocks of 1024/1024/512/512
//   w1p[m][1024] = [w1 even cols | w1 odd cols]
//   w2p[o][3072] = [w2 even | w2 odd | wsk even | wsk odd]
// gemm1: A=A2[:,2048:] (K=1024) x w1p -> h1=bn1(relu(.+b1)) into A2[:,1024:2048]
// gemm2: A=A2 (K=3072) x w2p -> out=bn2(relu(.+b2+bsk))  (skip folded into K)

#define BS   16384
#define DIN  512
#define MID  1024
#define NOUT 512
#define KA2  3072
#define BN_EPS 1e-5f

typedef __attribute__((ext_vector_type(8))) short bf16x8;
typedef __attribute__((ext_vector_type(4))) float floatx4;

#define GLDS(g, l) __builtin_amdgcn_global_load_lds( \
    (const __attribute__((address_space(1))) void*)(g), \
    (__attribute__((address_space(3))) void*)(l), 16, 0, 0)

__device__ __forceinline__ void cvt_store8(const float* __restrict__ src,
                                           __hip_bfloat16* __restrict__ dst) {
    float4 u = *(const float4*)src;
    float4 v = *(const float4*)(src + 4);
    __hip_bfloat16 tmp[8] __attribute__((aligned(16)));
    tmp[0] = __float2bfloat16(u.x); tmp[1] = __float2bfloat16(u.y);
    tmp[2] = __float2bfloat16(u.z); tmp[3] = __float2bfloat16(u.w);
    tmp[4] = __float2bfloat16(v.x); tmp[5] = __float2bfloat16(v.y);
    tmp[6] = __float2bfloat16(v.z); tmp[7] = __float2bfloat16(v.w);
    *(float4*)dst = *(const float4*)tmp;
}

// strided (every-other) fp32 -> 8 packed bf16
__device__ __forceinline__ void cvt_store8_s2(const float* __restrict__ src,
                                              __hip_bfloat16* __restrict__ dst) {
    __hip_bfloat16 tmp[8] __attribute__((aligned(16)));
#pragma unroll
    for (int i = 0; i < 8; ++i) tmp[i] = __float2bfloat16(src[2 * i]);
    *(float4*)dst = *(const float4*)tmp;
}

#define T_Q2  ((long)BS * 128)          // 2,097,152 threads: q2 -> A2[:,0:1024]
#define T_Q1X ((long)BS * 64)           // 1,048,576: q1 -> A2[:,2048:2560], x -> [:,2560:3072]
#define T_W1  (1024L * 1024 / 8)        //   131,072: w1 -> w1p
#define T_W2  (512L * 3072 / 8)         //   196,608: w2/wsk -> w2p
#define T_ALL (T_Q2 + T_Q1X + T_W1 + T_W2)   // 3,473,408 = 13568 * 256

__global__ __launch_bounds__(256) void prep_all_kernel(
    const float* __restrict__ x, const float* __restrict__ q1,
    const float* __restrict__ q2, const float* __restrict__ w1,
    const float* __restrict__ w2, const float* __restrict__ wsk,
    __hip_bfloat16* __restrict__ A2,
    __hip_bfloat16* __restrict__ w1p, __hip_bfloat16* __restrict__ w2p)
{
    long id = (long)blockIdx.x * 256 + threadIdx.x;
    if (id < T_Q2) {
        long b = id >> 7;
        int j = (int)(id & 127) << 3;
        cvt_store8(q2 + b * MID + j, A2 + b * KA2 + j);
    } else if (id < T_Q2 + T_Q1X) {
        long id2 = id - T_Q2;
        long b = id2 >> 6;
        int j = (int)(id2 & 63) << 3;
        cvt_store8(q1 + b * DIN + j, A2 + b * KA2 + 2048 + j);
        cvt_store8(x  + b * DIN + j, A2 + b * KA2 + 2560 + j);
    } else if (id < T_Q2 + T_Q1X + T_W1) {
        long t = id - (T_Q2 + T_Q1X);
        long o8 = t * 8;                       // output index in w1p
        int m = (int)(o8 >> 10), k0 = (int)(o8 & 1023);
        const float* src = w1 + m * 1024 + ((k0 < 512) ? 2 * k0 : 2 * (k0 - 512) + 1);
        cvt_store8_s2(src, w1p + o8);
    } else {
        long t = id - (T_Q2 + T_Q1X + T_W1);
        long o8 = t * 8;                       // output index in w2p
        int o = (int)(o8 / 3072), k0 = (int)(o8 - (long)o * 3072);
        const float* src;
        if (k0 < 1024)      src = w2 + o * 2048 + 2 * k0;
        else if (k0 < 2048) src = w2 + o * 2048 + 2 * (k0 - 1024) + 1;
        else if (k0 < 2560) src = wsk + o * 1024 + 2 * (k0 - 2048);
        else                src = wsk + o * 1024 + 2 * (k0 - 2560) + 1;
        cvt_store8_s2(src, w2p + o8);
    }
}

// ---------------------------------------------------------------------------
// shared schedule building blocks
// ---------------------------------------------------------------------------

#define PBAR() do { __builtin_amdgcn_sched_barrier(0); \
                    __builtin_amdgcn_s_barrier(); \
                    __builtin_amdgcn_sched_barrier(0); } while (0)
#define LGKM0() asm volatile("s_waitcnt lgkmcnt(0)" ::: "memory")
#define VMW(n)  asm volatile("s_waitcnt vmcnt(" #n ")" ::: "memory")

// ---------------------------------------------------------------------------
// gemm1: 256x256 tile, BK=64, 512 threads (8 waves = 2M x 4N), 8-phase
// schedule with counted vmcnt, raw s_barrier, LDS XOR swizzle on both sides.
// M=16384, N=1024, K=1024 -> grid 64x4 = 256 blocks = 1 block/CU.
// ---------------------------------------------------------------------------

// stage a full 256x64 bf16 K-tile (A or B operand) into LDS buf.
// phys chunk f = row*8 + cc holds logical chunk (row, cc ^ (row&7)):
// linear LDS dest (global_load_lds requirement) + inverse-swizzled source.
#define STAGE_TILE(G, STRIDE, ROWBLK, K0, LBASE) do { \
    _Pragma("unroll") for (int c_ = 0; c_ < 4; ++c_) { \
        int f0_ = (c_ * 8 + wave) * 64; \
        int f_  = f0_ + lane; \
        int sr_ = f_ >> 3, cc_ = f_ & 7; \
        GLDS((G) + (size_t)((ROWBLK) + sr_) * (STRIDE) + (K0) + ((cc_ ^ (sr_ & 7)) << 3), \
             ((short*)(LBASE)) + f0_ * 8); \
    } } while (0)

// read one i-half (4 M-frags x 2 k-slices) of this wave's A rows
#define READ_A(BUF, IH) do { \
    _Pragma("unroll") for (int i_ = 0; i_ < 4; ++i_) { \
        int r_ = wm * 128 + (IH) * 64 + i_ * 16 + (lane & 15); \
        _Pragma("unroll") for (int kk_ = 0; kk_ < 2; ++kk_) { \
            int cc_ = (kk_ * 4 + (lane >> 4)) ^ (r_ & 7); \
            a[i_][kk_] = *(const bf16x8*)&As[BUF][r_][cc_ * 8]; \
        } } } while (0)

// read one j-half (2 N-frags x 2 k-slices) of this wave's B rows
#define READ_B(BUF, JH) do { \
    _Pragma("unroll") for (int j_ = 0; j_ < 2; ++j_) { \
        int r_ = wn * 64 + (JH) * 32 + j_ * 16 + (lane & 15); \
        _Pragma("unroll") for (int kk_ = 0; kk_ < 2; ++kk_) { \
            int cc_ = (kk_ * 4 + (lane >> 4)) ^ (r_ & 7); \
            b[(JH) * 2 + j_][kk_] = *(const bf16x8*)&Bs[BUF][r_][cc_ * 8]; \
        } } } while (0)

// one C-quadrant: 4 i x 2 j x 2 kk = 16 MFMA, setprio-wrapped (T5)
#define MFMA_Q(IH, JH) do { \
    __builtin_amdgcn_s_setprio(1); \
    _Pragma("unroll") for (int i_ = 0; i_ < 4; ++i_) \
    _Pragma("unroll") for (int j_ = 0; j_ < 2; ++j_) \
    _Pragma("unroll") for (int kk_ = 0; kk_ < 2; ++kk_) \
        acc[(IH) * 4 + i_][(JH) * 2 + j_] = __builtin_amdgcn_mfma_f32_16x16x32_bf16( \
            a[i_][kk_], b[(JH) * 2 + j_][kk_], acc[(IH) * 4 + i_][(JH) * 2 + j_], 0, 0, 0); \
    __builtin_amdgcn_s_setprio(0); \
} while (0)

__global__ __launch_bounds__(512, 2) void gemm1_8ph(
    const __hip_bfloat16* __restrict__ Ag,   // A2 + 2048, row stride KA2
    const __hip_bfloat16* __restrict__ Bg,   // w1p, row stride 1024
    const float* __restrict__ bias,
    const float* __restrict__ bn_s, const float* __restrict__ bn_b,
    const float* __restrict__ bn_m, const float* __restrict__ bn_v,
    __hip_bfloat16* __restrict__ hout)       // A2 + 1024, row stride KA2
{
    __shared__ __align__(16) short As[2][256][64];   // 64 KiB
    __shared__ __align__(16) short Bs[2][256][64];   // 64 KiB

    const int t = threadIdx.x;
    const int lane = t & 63;
    const int wave = t >> 6;        // 0..7
    const int wm = wave >> 2;       // 0..1 : wave row  (128 rows each)
    const int wn = wave & 3;        // 0..3 : wave col  (64 cols each)

    const int p = blockIdx.x;
    const int m0 = ((p & 7) + 8 * ((p >> 3) & 7)) * 256;
    const int n0 = (p >> 6) * 256;

    floatx4 acc[8][4];
#pragma unroll
    for (int i = 0; i < 8; ++i)
#pragma unroll
        for (int j = 0; j < 4; ++j)
            acc[i][j] = (floatx4){0.f, 0.f, 0.f, 0.f};

    bf16x8 a[4][2], b[4][2];

    // prologue: stage K-tiles 0 (buf0) and 1 (buf1), full drain once.
    STAGE_TILE(Bg, 1024, n0, 0,  Bs[0]);
    STAGE_TILE(Ag, KA2,  m0, 0,  As[0]);
    STAGE_TILE(Bg, 1024, n0, 64, Bs[1]);
    STAGE_TILE(Ag, KA2,  m0, 64, As[1]);
    VMW(0);
    __builtin_amdgcn_s_barrier();

    for (int it = 0; it < 8; ++it) {
        const bool more = (it < 7);
        const int kn = it * 128 + 128;

        // ---- P1: Q(0,0)
        READ_A(0, 0); READ_B(0, 0);
        PBAR(); LGKM0(); MFMA_Q(0, 0); PBAR();
        // ---- P2: Q(0,1)
        READ_B(0, 1);
        PBAR(); LGKM0(); MFMA_Q(0, 1); PBAR();
        // ---- P3: Q(1,1)  + stage next B tile (buf0 B fully read at P2)
        READ_A(0, 1);
        if (more) STAGE_TILE(Bg, 1024, n0, kn, Bs[0]);
        PBAR(); LGKM0(); MFMA_Q(1, 1); PBAR();
        // ---- P4: Q(1,0)  + wait + stage next A tile (buf0 A read at P3)
        if (more) { VMW(4); } else { VMW(0); }
        if (more) STAGE_TILE(Ag, KA2, m0, kn, As[0]);
        PBAR(); MFMA_Q(1, 0); PBAR();

        // ---- P5: Q(0,0) on buf1
        READ_A(1, 0); READ_B(1, 0);
        PBAR(); LGKM0(); MFMA_Q(0, 0); PBAR();
        // ---- P6: Q(0,1)
        READ_B(1, 1);
        PBAR(); LGKM0(); MFMA_Q(0, 1); PBAR();
        // ---- P7: Q(1,1)  + stage next B tile (buf1)
        READ_A(1, 1);
        if (more) STAGE_TILE(Bg, 1024, n0, kn + 64, Bs[1]);
        PBAR(); LGKM0(); MFMA_Q(1, 1); PBAR();
        // ---- P8: Q(1,0)  + wait + stage next A tile (buf1)
        VMW(4);
        if (more) STAGE_TILE(Ag, KA2, m0, kn + 64, As[1]);
        PBAR(); MFMA_Q(1, 0); PBAR();
    }

    // epilogue: bn1(relu(+b1)) -> bf16 into A2[:,1024:2048]
#pragma unroll
    for (int j = 0; j < 4; ++j) {
        int col = n0 + wn * 64 + j * 16 + (lane & 15);
        float bias_v = bias[col];
        float scale = bn_s[col] * rsqrtf(bn_v[col] + BN_EPS);
        float mean = bn_m[col], beta = bn_b[col];
#pragma unroll
        for (int i = 0; i < 8; ++i) {
            int rbase = m0 + wm * 128 + i * 16 + (lane >> 4) * 4;
#pragma unroll
            for (int r = 0; r < 4; ++r) {
                float v = acc[i][j][r] + bias_v;
                v = fmaxf(v, 0.f);
                v = (v - mean) * scale + beta;
                hout[(size_t)(rbase + r) * KA2 + col] = __float2bfloat16(v);
            }
        }
    }
}

// ---------------------------------------------------------------------------
// gemm2: 256x128 tile, BK=64, 512 threads (8 waves = 2M x 4N, wave tile
// 128x32), 4 phases per iteration over 2 K-tiles, counted vmcnt(2).
// Stage plan (per iter): P1: A->buf1 (tile 2it+1), P2: B->buf0 (2it+2),
// P3: A->buf0 (2it+2), P4: B->buf1 (2it+3). A tile = 4 GLDS, B tile = 2.
// Steady outstanding at P1/P3 entry = 8; vmcnt(2) retires exactly the 6
// loads of the buffer about to be read. Final iter: vmcnt(0) at P3.
// M=16384, N=512, K=3072 -> grid 64x4 = 256 blocks = 1 block/CU.
// ---------------------------------------------------------------------------

#define STAGE_A2T(K0, LBASE) do { \
    _Pragma("unroll") for (int c_ = 0; c_ < 4; ++c_) { \
        int f0_ = (c_ * 8 + wave) * 64; \
        int f_  = f0_ + lane; \
        int sr_ = f_ >> 3, cc_ = f_ & 7; \
        GLDS(Ag + (size_t)(m0 + sr_) * KA2 + (K0) + ((cc_ ^ (sr_ & 7)) << 3), \
             ((short*)(LBASE)) + f0_ * 8); \
    } } while (0)

#define STAGE_B2T(K0, LBASE) do { \
    _Pragma("unroll") for (int c_ = 0; c_ < 2; ++c_) { \
        int f0_ = (c_ * 8 + wave) * 64; \
        int f_  = f0_ + lane; \
        int sr_ = f_ >> 3, cc_ = f_ & 7; \
        GLDS(Bg + (size_t)(n0 + sr_) * KA2 + (K0) + ((cc_ ^ (sr_ & 7)) << 3), \
             ((short*)(LBASE)) + f0_ * 8); \
    } } while (0)

#define READ_A2G(BUF, IH) do { \
    _Pragma("unroll") for (int i_ = 0; i_ < 4; ++i_) { \
        int r_ = wm * 128 + (IH) * 64 + i_ * 16 + (lane & 15); \
        _Pragma("unroll") for (int kk_ = 0; kk_ < 2; ++kk_) { \
            int cc_ = (kk_ * 4 + (lane >> 4)) ^ (r_ & 7); \
            a[i_][kk_] = *(const bf16x8*)&As2[BUF][r_][cc_ * 8]; \
        } } } while (0)

#define READ_B2G(BUF) do { \
    _Pragma("unroll") for (int j_ = 0; j_ < 2; ++j_) { \
        int r_ = wn * 32 + j_ * 16 + (lane & 15); \
        _Pragma("unroll") for (int kk_ = 0; kk_ < 2; ++kk_) { \
            int cc_ = (kk_ * 4 + (lane >> 4)) ^ (r_ & 7); \
            br[j_][kk_] = *(const bf16x8*)&Bs2[BUF][r_][cc_ * 8]; \
        } } } while (0)

// one i-half x full j: 4i x 2j x 2kk = 16 MFMA
#define MFMA_H(IH) do { \
    __builtin_amdgcn_s_setprio(1); \
    _Pragma("unroll") for (int i_ = 0; i_ < 4; ++i_) \
    _Pragma("unroll") for (int j_ = 0; j_ < 2; ++j_) \
    _Pragma("unroll") for (int kk_ = 0; kk_ < 2; ++kk_) \
        acc[(IH) * 4 + i_][j_] = __builtin_amdgcn_mfma_f32_16x16x32_bf16( \
            a[i_][kk_], br[j_][kk_], acc[(IH) * 4 + i_][j_], 0, 0, 0); \
    __builtin_amdgcn_s_setprio(0); \
} while (0)

__global__ __launch_bounds__(512, 2) void gemm2_8ph(
    const __hip_bfloat16* __restrict__ Ag,   // A2, row stride KA2, K=3072
    const __hip_bfloat16* __restrict__ Bg,   // w2p, row stride KA2
    const float* __restrict__ bias_a, const float* __restrict__ bias_b,
    const float* __restrict__ bn_s, const float* __restrict__ bn_b,
    const float* __restrict__ bn_m, const float* __restrict__ bn_v,
    float* __restrict__ fout)                // out, row stride NOUT
{
    __shared__ __align__(16) short As2[2][256][64];  // 64 KiB
    __shared__ __align__(16) short Bs2[2][128][64];  // 32 KiB

    const int t = threadIdx.x;
    const int lane = t & 63;
    const int wave = t >> 6;        // 0..7
    const int wm = wave >> 2;       // 0..1 : 128 rows each
    const int wn = wave & 3;        // 0..3 : 32 cols each

    // 256 blocks = 64 M-strips x 4 N-blocks; all 4 N-blocks of an M-strip
    // share (p&7) -> same XCD -> A-strip (1.5 MB) stays L2-resident.
    const int p = blockIdx.x;
    const int m0 = ((p & 7) + 8 * ((p >> 3) & 7)) * 256;
    const int n0 = (p >> 6) * 128;

    floatx4 acc[8][2];
#pragma unroll
    for (int i = 0; i < 8; ++i)
#pragma unroll
        for (int j = 0; j < 2; ++j)
            acc[i][j] = (floatx4){0.f, 0.f, 0.f, 0.f};

    bf16x8 a[4][2], br[2][2];

    // prologue: tile0 (B+A) -> buf0, tile1 B -> buf1 (tile1 A staged at it0-P1)
    STAGE_B2T(0,  Bs2[0]);
    STAGE_A2T(0,  As2[0]);
    STAGE_B2T(64, Bs2[1]);
    VMW(0);
    __builtin_amdgcn_s_barrier();

    for (int it = 0; it < 24; ++it) {
        const bool more = (it < 23);
        const int kn = it * 128;     // buf0 holds tile k=kn, buf1 k=kn+64

        // ---- P1: buf0 A-h0 + B; stage A(tile kn+64 -> buf1)
        VMW(2);
        READ_A2G(0, 0); READ_B2G(0);
        STAGE_A2T(kn + 64, As2[1]);
        PBAR(); LGKM0(); MFMA_H(0); PBAR();
        // ---- P2: buf0 A-h1; stage B(tile kn+128 -> buf0)
        READ_A2G(0, 1);
        if (more) STAGE_B2T(kn + 128, Bs2[0]);
        PBAR(); LGKM0(); MFMA_H(1); PBAR();
        // ---- P3: buf1 A-h0 + B; stage A(tile kn+128 -> buf0)
        if (more) { VMW(2); } else { VMW(0); }
        READ_A2G(1, 0); READ_B2G(1);
        if (more) STAGE_A2T(kn + 128, As2[0]);
        PBAR(); LGKM0(); MFMA_H(0); PBAR();
        // ---- P4: buf1 A-h1; stage B(tile kn+192 -> buf1)
        READ_A2G(1, 1);
        if (more) STAGE_B2T(kn + 192, Bs2[1]);
        PBAR(); LGKM0(); MFMA_H(1); PBAR();
    }

    // epilogue: bn2(relu(+b2+bsk)) -> fp32 out
#pragma unroll
    for (int j = 0; j < 2; ++j) {
        int col = n0 + wn * 32 + j * 16 + (lane & 15);
        float bias_v = bias_a[col] + bias_b[col];
        float scale = bn_s[col] * rsqrtf(bn_v[col] + BN_EPS);
        float mean = bn_m[col], beta = bn_b[col];
#pragma unroll
        for (int i = 0; i < 8; ++i) {
            int rbase = m0 + wm * 128 + i * 16 + (lane >> 4) * 4;
#pragma unroll
            for (int r = 0; r < 4; ++r) {
                float v = acc[i][j][r] + bias_v;
                v = fmaxf(v, 0.f);
                v = (v - mean) * scale + beta;
                fout[(size_t)(rbase + r) * NOUT + col] = v;
            }
        }
    }
}

extern "C" void kernel_launch(void* const* d_in, const int* in_sizes, int n_in,
                              void* d_out, int out_size, void* d_ws, size_t ws_size,
                              hipStream_t stream) {
    const float* x   = (const float*)d_in[0];
    const float* q1  = (const float*)d_in[1];
    const float* q2  = (const float*)d_in[2];
    const float* w1  = (const float*)d_in[3];
    const float* b1  = (const float*)d_in[4];
    const float* w2  = (const float*)d_in[5];
    const float* b2  = (const float*)d_in[6];
    const float* wsk = (const float*)d_in[7];
    const float* bsk = (const float*)d_in[8];
    const float* s1  = (const float*)d_in[9];
    const float* bb1 = (const float*)d_in[10];
    const float* m1  = (const float*)d_in[11];
    const float* v1  = (const float*)d_in[12];
    const float* s2  = (const float*)d_in[13];
    const float* bb2 = (const float*)d_in[14];
    const float* m2  = (const float*)d_in[15];
    const float* v2  = (const float*)d_in[16];
    float* out = (float*)d_out;

    size_t needA2 = (size_t)BS * KA2 * sizeof(__hip_bfloat16);
    size_t needW  = ((size_t)1024 * 1024 + (size_t)512 * 3072) * sizeof(__hip_bfloat16);
    char* base;
    if (ws_size >= needA2 + needW)
        base = (char*)d_ws;
    else
        base = (char*)d_in[2] + (size_t)BS * MID * sizeof(float);
    __hip_bfloat16* A2  = (__hip_bfloat16*)base;
    __hip_bfloat16* w1p = (__hip_bfloat16*)(base + needA2);
    __hip_bfloat16* w2p = w1p + 1024 * 1024;

    prep_all_kernel<<<dim3((int)(T_ALL / 256)), dim3(256), 0, stream>>>(
        x, q1, q2, w1, w2, wsk, A2, w1p, w2p);

    // gemm1: M=16384, N=1024, K=1024; h1 -> A2[:,1024:2048]  (8-phase 256^2)
    gemm1_8ph<<<dim3(256), dim3(512), 0, stream>>>(
        A2 + 2048, w1p, b1, s1, bb1, m1, v1, A2 + 1024);

    // gemm2: M=16384, N=512, K=3072 (w2 + skip folded); out fp32 (8-phase 256x128)
    gemm2_8ph<<<dim3(256), dim3(512), 0, stream>>>(
        A2, w2p, b2, bsk, s2, bb2, m2, v2, out);
}

// Round 3
// 515.558 us; speedup vs baseline: 1.0580x; 1.0021x over previous
//
#include <hip/hip_runtime.h>
#include <hip/hip_bf16.h>

// AutoregressiveResidualBlock — Round 5: gemm2 rebuilt with a 3-deep A
// pipeline (As2[3], stage 2 K-tiles ahead) and race-free vmcnt placement
// (single vmcnt(6) immediately before the phase barrier, so every fresh
// LDS buffer is read only after ALL waves' global_load_lds are retired).
// Removes the ~500cy/2-tile HBM-latency stall of the round-4 schedule.
// gemm1 (verified 256^2 8-phase) and prep unchanged.
//
// Layout (K-permutation; GEMM invariant under shared K-perm of A and B):
//   A2[b][k] (bf16, stride 3072): [q2 | h1 | q1 | x] blocks of 1024/1024/512/512
//   w1p[m][1024] = [w1 even cols | w1 odd cols]
//   w2p[o][3072] = [w2 even | w2 odd | wsk even | wsk odd]
// gemm1: A=A2[:,2048:] (K=1024) x w1p -> h1=bn1(relu(.+b1)) into A2[:,1024:2048]
// gemm2: A=A2 (K=3072) x w2p -> out=bn2(relu(.+b2+bsk))  (skip folded into K)

#define BS   16384
#define DIN  512
#define MID  1024
#define NOUT 512
#define KA2  3072
#define BN_EPS 1e-5f

typedef __attribute__((ext_vector_type(8))) short bf16x8;
typedef __attribute__((ext_vector_type(4))) float floatx4;

#define GLDS(g, l) __builtin_amdgcn_global_load_lds( \
    (const __attribute__((address_space(1))) void*)(g), \
    (__attribute__((address_space(3))) void*)(l), 16, 0, 0)

__device__ __forceinline__ void cvt_store8(const float* __restrict__ src,
                                           __hip_bfloat16* __restrict__ dst) {
    float4 u = *(const float4*)src;
    float4 v = *(const float4*)(src + 4);
    __hip_bfloat16 tmp[8] __attribute__((aligned(16)));
    tmp[0] = __float2bfloat16(u.x); tmp[1] = __float2bfloat16(u.y);
    tmp[2] = __float2bfloat16(u.z); tmp[3] = __float2bfloat16(u.w);
    tmp[4] = __float2bfloat16(v.x); tmp[5] = __float2bfloat16(v.y);
    tmp[6] = __float2bfloat16(v.z); tmp[7] = __float2bfloat16(v.w);
    *(float4*)dst = *(const float4*)tmp;
}

// strided (every-other) fp32 -> 8 packed bf16
__device__ __forceinline__ void cvt_store8_s2(const float* __restrict__ src,
                                              __hip_bfloat16* __restrict__ dst) {
    __hip_bfloat16 tmp[8] __attribute__((aligned(16)));
#pragma unroll
    for (int i = 0; i < 8; ++i) tmp[i] = __float2bfloat16(src[2 * i]);
    *(float4*)dst = *(const float4*)tmp;
}

#define T_Q2  ((long)BS * 128)          // 2,097,152 threads: q2 -> A2[:,0:1024]
#define T_Q1X ((long)BS * 64)           // 1,048,576: q1 -> A2[:,2048:2560], x -> [:,2560:3072]
#define T_W1  (1024L * 1024 / 8)        //   131,072: w1 -> w1p
#define T_W2  (512L * 3072 / 8)         //   196,608: w2/wsk -> w2p
#define T_ALL (T_Q2 + T_Q1X + T_W1 + T_W2)   // 3,473,408 = 13568 * 256

__global__ __launch_bounds__(256) void prep_all_kernel(
    const float* __restrict__ x, const float* __restrict__ q1,
    const float* __restrict__ q2, const float* __restrict__ w1,
    const float* __restrict__ w2, const float* __restrict__ wsk,
    __hip_bfloat16* __restrict__ A2,
    __hip_bfloat16* __restrict__ w1p, __hip_bfloat16* __restrict__ w2p)
{
    long id = (long)blockIdx.x * 256 + threadIdx.x;
    if (id < T_Q2) {
        long b = id >> 7;
        int j = (int)(id & 127) << 3;
        cvt_store8(q2 + b * MID + j, A2 + b * KA2 + j);
    } else if (id < T_Q2 + T_Q1X) {
        long id2 = id - T_Q2;
        long b = id2 >> 6;
        int j = (int)(id2 & 63) << 3;
        cvt_store8(q1 + b * DIN + j, A2 + b * KA2 + 2048 + j);
        cvt_store8(x  + b * DIN + j, A2 + b * KA2 + 2560 + j);
    } else if (id < T_Q2 + T_Q1X + T_W1) {
        long t = id - (T_Q2 + T_Q1X);
        long o8 = t * 8;                       // output index in w1p
        int m = (int)(o8 >> 10), k0 = (int)(o8 & 1023);
        const float* src = w1 + m * 1024 + ((k0 < 512) ? 2 * k0 : 2 * (k0 - 512) + 1);
        cvt_store8_s2(src, w1p + o8);
    } else {
        long t = id - (T_Q2 + T_Q1X + T_W1);
        long o8 = t * 8;                       // output index in w2p
        int o = (int)(o8 / 3072), k0 = (int)(o8 - (long)o * 3072);
        const float* src;
        if (k0 < 1024)      src = w2 + o * 2048 + 2 * k0;
        else if (k0 < 2048) src = w2 + o * 2048 + 2 * (k0 - 1024) + 1;
        else if (k0 < 2560) src = wsk + o * 1024 + 2 * (k0 - 2048);
        else                src = wsk + o * 1024 + 2 * (k0 - 2560) + 1;
        cvt_store8_s2(src, w2p + o8);
    }
}

// ---------------------------------------------------------------------------
// shared schedule building blocks
// ---------------------------------------------------------------------------

#define PBAR() do { __builtin_amdgcn_sched_barrier(0); \
                    __builtin_amdgcn_s_barrier(); \
                    __builtin_amdgcn_sched_barrier(0); } while (0)
#define LGKM0() asm volatile("s_waitcnt lgkmcnt(0)" ::: "memory")
#define VMW(n)  asm volatile("s_waitcnt vmcnt(" #n ")" ::: "memory")

// ---------------------------------------------------------------------------
// gemm1: 256x256 tile, BK=64, 512 threads (8 waves = 2M x 4N), 8-phase
// schedule with counted vmcnt, raw s_barrier, LDS XOR swizzle on both sides.
// M=16384, N=1024, K=1024 -> grid 64x4 = 256 blocks = 1 block/CU.
// Race-free: every fresh-buffer read follows a (VMW -> s_barrier) pair
// (P4/P8 place VMW immediately before their barrier).
// ---------------------------------------------------------------------------

// stage a full 256x64 bf16 K-tile (A or B operand) into LDS buf.
// phys chunk f = row*8 + cc holds logical chunk (row, cc ^ (row&7)):
// linear LDS dest (global_load_lds requirement) + inverse-swizzled source.
#define STAGE_TILE(G, STRIDE, ROWBLK, K0, LBASE) do { \
    _Pragma("unroll") for (int c_ = 0; c_ < 4; ++c_) { \
        int f0_ = (c_ * 8 + wave) * 64; \
        int f_  = f0_ + lane; \
        int sr_ = f_ >> 3, cc_ = f_ & 7; \
        GLDS((G) + (size_t)((ROWBLK) + sr_) * (STRIDE) + (K0) + ((cc_ ^ (sr_ & 7)) << 3), \
             ((short*)(LBASE)) + f0_ * 8); \
    } } while (0)

// read one i-half (4 M-frags x 2 k-slices) of this wave's A rows
#define READ_A(BUF, IH) do { \
    _Pragma("unroll") for (int i_ = 0; i_ < 4; ++i_) { \
        int r_ = wm * 128 + (IH) * 64 + i_ * 16 + (lane & 15); \
        _Pragma("unroll") for (int kk_ = 0; kk_ < 2; ++kk_) { \
            int cc_ = (kk_ * 4 + (lane >> 4)) ^ (r_ & 7); \
            a[i_][kk_] = *(const bf16x8*)&As[BUF][r_][cc_ * 8]; \
        } } } while (0)

// read one j-half (2 N-frags x 2 k-slices) of this wave's B rows
#define READ_B(BUF, JH) do { \
    _Pragma("unroll") for (int j_ = 0; j_ < 2; ++j_) { \
        int r_ = wn * 64 + (JH) * 32 + j_ * 16 + (lane & 15); \
        _Pragma("unroll") for (int kk_ = 0; kk_ < 2; ++kk_) { \
            int cc_ = (kk_ * 4 + (lane >> 4)) ^ (r_ & 7); \
            b[(JH) * 2 + j_][kk_] = *(const bf16x8*)&Bs[BUF][r_][cc_ * 8]; \
        } } } while (0)

// one C-quadrant: 4 i x 2 j x 2 kk = 16 MFMA, setprio-wrapped (T5)
#define MFMA_Q(IH, JH) do { \
    __builtin_amdgcn_s_setprio(1); \
    _Pragma("unroll") for (int i_ = 0; i_ < 4; ++i_) \
    _Pragma("unroll") for (int j_ = 0; j_ < 2; ++j_) \
    _Pragma("unroll") for (int kk_ = 0; kk_ < 2; ++kk_) \
        acc[(IH) * 4 + i_][(JH) * 2 + j_] = __builtin_amdgcn_mfma_f32_16x16x32_bf16( \
            a[i_][kk_], b[(JH) * 2 + j_][kk_], acc[(IH) * 4 + i_][(JH) * 2 + j_], 0, 0, 0); \
    __builtin_amdgcn_s_setprio(0); \
} while (0)

__global__ __launch_bounds__(512, 2) void gemm1_8ph(
    const __hip_bfloat16* __restrict__ Ag,   // A2 + 2048, row stride KA2
    const __hip_bfloat16* __restrict__ Bg,   // w1p, row stride 1024
    const float* __restrict__ bias,
    const float* __restrict__ bn_s, const float* __restrict__ bn_b,
    const float* __restrict__ bn_m, const float* __restrict__ bn_v,
    __hip_bfloat16* __restrict__ hout)       // A2 + 1024, row stride KA2
{
    __shared__ __align__(16) short As[2][256][64];   // 64 KiB
    __shared__ __align__(16) short Bs[2][256][64];   // 64 KiB

    const int t = threadIdx.x;
    const int lane = t & 63;
    const int wave = t >> 6;        // 0..7
    const int wm = wave >> 2;       // 0..1 : wave row  (128 rows each)
    const int wn = wave & 3;        // 0..3 : wave col  (64 cols each)

    const int p = blockIdx.x;
    const int m0 = ((p & 7) + 8 * ((p >> 3) & 7)) * 256;
    const int n0 = (p >> 6) * 256;

    floatx4 acc[8][4];
#pragma unroll
    for (int i = 0; i < 8; ++i)
#pragma unroll
        for (int j = 0; j < 4; ++j)
            acc[i][j] = (floatx4){0.f, 0.f, 0.f, 0.f};

    bf16x8 a[4][2], b[4][2];

    // prologue: stage K-tiles 0 (buf0) and 1 (buf1), full drain once.
    STAGE_TILE(Bg, 1024, n0, 0,  Bs[0]);
    STAGE_TILE(Ag, KA2,  m0, 0,  As[0]);
    STAGE_TILE(Bg, 1024, n0, 64, Bs[1]);
    STAGE_TILE(Ag, KA2,  m0, 64, As[1]);
    VMW(0);
    __builtin_amdgcn_s_barrier();

    for (int it = 0; it < 8; ++it) {
        const bool more = (it < 7);
        const int kn = it * 128 + 128;

        // ---- P1: Q(0,0)
        READ_A(0, 0); READ_B(0, 0);
        PBAR(); LGKM0(); MFMA_Q(0, 0); PBAR();
        // ---- P2: Q(0,1)
        READ_B(0, 1);
        PBAR(); LGKM0(); MFMA_Q(0, 1); PBAR();
        // ---- P3: Q(1,1)  + stage next B tile (buf0 B fully read at P2)
        READ_A(0, 1);
        if (more) STAGE_TILE(Bg, 1024, n0, kn, Bs[0]);
        PBAR(); LGKM0(); MFMA_Q(1, 1); PBAR();
        // ---- P4: Q(1,0)  + wait + stage next A tile (buf0 A read at P3)
        if (more) { VMW(4); } else { VMW(0); }
        if (more) STAGE_TILE(Ag, KA2, m0, kn, As[0]);
        PBAR(); MFMA_Q(1, 0); PBAR();

        // ---- P5: Q(0,0) on buf1
        READ_A(1, 0); READ_B(1, 0);
        PBAR(); LGKM0(); MFMA_Q(0, 0); PBAR();
        // ---- P6: Q(0,1)
        READ_B(1, 1);
        PBAR(); LGKM0(); MFMA_Q(0, 1); PBAR();
        // ---- P7: Q(1,1)  + stage next B tile (buf1)
        READ_A(1, 1);
        if (more) STAGE_TILE(Bg, 1024, n0, kn + 64, Bs[1]);
        PBAR(); LGKM0(); MFMA_Q(1, 1); PBAR();
        // ---- P8: Q(1,0)  + wait + stage next A tile (buf1)
        VMW(4);
        if (more) STAGE_TILE(Ag, KA2, m0, kn + 64, As[1]);
        PBAR(); MFMA_Q(1, 0); PBAR();
    }

    // epilogue: bn1(relu(+b1)) -> bf16 into A2[:,1024:2048]
#pragma unroll
    for (int j = 0; j < 4; ++j) {
        int col = n0 + wn * 64 + j * 16 + (lane & 15);
        float bias_v = bias[col];
        float scale = bn_s[col] * rsqrtf(bn_v[col] + BN_EPS);
        float mean = bn_m[col], beta = bn_b[col];
#pragma unroll
        for (int i = 0; i < 8; ++i) {
            int rbase = m0 + wm * 128 + i * 16 + (lane >> 4) * 4;
#pragma unroll
            for (int r = 0; r < 4; ++r) {
                float v = acc[i][j][r] + bias_v;
                v = fmaxf(v, 0.f);
                v = (v - mean) * scale + beta;
                hout[(size_t)(rbase + r) * KA2 + col] = __float2bfloat16(v);
            }
        }
    }
}

// ---------------------------------------------------------------------------
// gemm2: 256x128 tile, BK=64, 512 threads (8 waves = 2M x 4N, wave tile
// 128x32). Per-tile 2-phase schedule, 48 K-tiles, 3-deep A double...triple
// buffer (As2[3]) + 2-deep B (Bs2[2]); A and B both staged 2 tiles ahead.
// vmcnt ledger (loads/tile: A=4, B=2, issue order ...A(t+1),B(t+1),
// A(t+2)@tP1,B(t+2)@tP2): at tile-t P2 the queue is 12; VMW(6) retires
// exactly A(t+1)+B(t+1) and sits IMMEDIATELY before the phase barrier, so
// tile t+1's reads (after the barrier) are race-free for all waves.
// Stage wait distance = 2 tiles (~4 phases ~ 1700cy) > ~900cy HBM latency.
// Tail: t>=46 stages nothing and drains with VMW(0).
// M=16384, N=512, K=3072 -> grid 64x4 = 256 blocks = 1 block/CU.
// ---------------------------------------------------------------------------

#define STAGE_A2T(K0, LBASE) do { \
    _Pragma("unroll") for (int c_ = 0; c_ < 4; ++c_) { \
        int f0_ = (c_ * 8 + wave) * 64; \
        int f_  = f0_ + lane; \
        int sr_ = f_ >> 3, cc_ = f_ & 7; \
        GLDS(Ag + (size_t)(m0 + sr_) * KA2 + (K0) + ((cc_ ^ (sr_ & 7)) << 3), \
             ((short*)(LBASE)) + f0_ * 8); \
    } } while (0)

#define STAGE_B2T(K0, LBASE) do { \
    _Pragma("unroll") for (int c_ = 0; c_ < 2; ++c_) { \
        int f0_ = (c_ * 8 + wave) * 64; \
        int f_  = f0_ + lane; \
        int sr_ = f_ >> 3, cc_ = f_ & 7; \
        GLDS(Bg + (size_t)(n0 + sr_) * KA2 + (K0) + ((cc_ ^ (sr_ & 7)) << 3), \
             ((short*)(LBASE)) + f0_ * 8); \
    } } while (0)

#define READ_A2G(BUF, IH) do { \
    _Pragma("unroll") for (int i_ = 0; i_ < 4; ++i_) { \
        int r_ = wm * 128 + (IH) * 64 + i_ * 16 + (lane & 15); \
        _Pragma("unroll") for (int kk_ = 0; kk_ < 2; ++kk_) { \
            int cc_ = (kk_ * 4 + (lane >> 4)) ^ (r_ & 7); \
            a[i_][kk_] = *(const bf16x8*)&As2[BUF][r_][cc_ * 8]; \
        } } } while (0)

#define READ_B2G(BUF) do { \
    _Pragma("unroll") for (int j_ = 0; j_ < 2; ++j_) { \
        int r_ = wn * 32 + j_ * 16 + (lane & 15); \
        _Pragma("unroll") for (int kk_ = 0; kk_ < 2; ++kk_) { \
            int cc_ = (kk_ * 4 + (lane >> 4)) ^ (r_ & 7); \
            br[j_][kk_] = *(const bf16x8*)&Bs2[BUF][r_][cc_ * 8]; \
        } } } while (0)

// one i-half x full j: 4i x 2j x 2kk = 16 MFMA
#define MFMA_H(IH) do { \
    __builtin_amdgcn_s_setprio(1); \
    _Pragma("unroll") for (int i_ = 0; i_ < 4; ++i_) \
    _Pragma("unroll") for (int j_ = 0; j_ < 2; ++j_) \
    _Pragma("unroll") for (int kk_ = 0; kk_ < 2; ++kk_) \
        acc[(IH) * 4 + i_][j_] = __builtin_amdgcn_mfma_f32_16x16x32_bf16( \
            a[i_][kk_], br[j_][kk_], acc[(IH) * 4 + i_][j_], 0, 0, 0); \
    __builtin_amdgcn_s_setprio(0); \
} while (0)

// one K-tile T (k offset T*64), A-buf BA = T%3, B-buf BB = T%2.
// P1: read A-h0 + all B of tile T; stage A(T+2) -> As2[(BA+2)%3]
//     (that buf's last reads finished at tile T-1 P2, one barrier ago).
// P2: read A-h1; stage B(T+2) -> Bs2[BB] (read-complete since P1's LGKM0);
//     VMW(6) -> barrier: retires A(T+1),B(T+1) for the next tile's reads.
#define TILE2(T, BA, BB) do { \
    const bool st_ = ((T) + 2 < 48); \
    READ_A2G(BA, 0); READ_B2G(BB); \
    if (st_) STAGE_A2T(((T) + 2) * 64, As2[((BA) + 2) % 3]); \
    PBAR(); LGKM0(); MFMA_H(0); PBAR(); \
    READ_A2G(BA, 1); \
    if (st_) STAGE_B2T(((T) + 2) * 64, Bs2[BB]); \
    if (st_) { VMW(6); } else { VMW(0); } \
    PBAR(); LGKM0(); MFMA_H(1); PBAR(); \
} while (0)

__global__ __launch_bounds__(512, 2) void gemm2_8ph(
    const __hip_bfloat16* __restrict__ Ag,   // A2, row stride KA2, K=3072
    const __hip_bfloat16* __restrict__ Bg,   // w2p, row stride KA2
    const float* __restrict__ bias_a, const float* __restrict__ bias_b,
    const float* __restrict__ bn_s, const float* __restrict__ bn_b,
    const float* __restrict__ bn_m, const float* __restrict__ bn_v,
    float* __restrict__ fout)                // out, row stride NOUT
{
    __shared__ __align__(16) short As2[3][256][64];  // 96 KiB
    __shared__ __align__(16) short Bs2[2][128][64];  // 32 KiB

    const int t = threadIdx.x;
    const int lane = t & 63;
    const int wave = t >> 6;        // 0..7
    const int wm = wave >> 2;       // 0..1 : 128 rows each
    const int wn = wave & 3;        // 0..3 : 32 cols each

    // 256 blocks = 64 M-strips x 4 N-blocks; all 4 N-blocks of an M-strip
    // share (p&7) -> same XCD -> A-strip (1.5 MB) stays L2-resident.
    const int p = blockIdx.x;
    const int m0 = ((p & 7) + 8 * ((p >> 3) & 7)) * 256;
    const int n0 = (p >> 6) * 128;

    floatx4 acc[8][2];
#pragma unroll
    for (int i = 0; i < 8; ++i)
#pragma unroll
        for (int j = 0; j < 2; ++j)
            acc[i][j] = (floatx4){0.f, 0.f, 0.f, 0.f};

    bf16x8 a[4][2], br[2][2];

    // prologue: stage tiles 0 and 1 (issue order B0 A0 B1 A1 = 12 loads);
    // VMW(6) retires exactly B0+A0 (oldest 6) -> barrier -> tile0 reads safe.
    STAGE_B2T(0,  Bs2[0]);
    STAGE_A2T(0,  As2[0]);
    STAGE_B2T(64, Bs2[1]);
    STAGE_A2T(64, As2[1]);
    VMW(6);
    __builtin_amdgcn_s_barrier();

#pragma unroll 1
    for (int s = 0; s < 8; ++s) {
        const int kt = s * 6;       // tiles kt..kt+5; (kt)%3==0, (kt)%2==0
        TILE2(kt + 0, 0, 0);
        TILE2(kt + 1, 1, 1);
        TILE2(kt + 2, 2, 0);
        TILE2(kt + 3, 0, 1);
        TILE2(kt + 4, 1, 0);
        TILE2(kt + 5, 2, 1);
    }

    // epilogue: bn2(relu(+b2+bsk)) -> fp32 out
#pragma unroll
    for (int j = 0; j < 2; ++j) {
        int col = n0 + wn * 32 + j * 16 + (lane & 15);
        float bias_v = bias_a[col] + bias_b[col];
        float scale = bn_s[col] * rsqrtf(bn_v[col] + BN_EPS);
        float mean = bn_m[col], beta = bn_b[col];
#pragma unroll
        for (int i = 0; i < 8; ++i) {
            int rbase = m0 + wm * 128 + i * 16 + (lane >> 4) * 4;
#pragma unroll
            for (int r = 0; r < 4; ++r) {
                float v = acc[i][j][r] + bias_v;
                v = fmaxf(v, 0.f);
                v = (v - mean) * scale + beta;
                fout[(size_t)(rbase + r) * NOUT + col] = v;
            }
        }
    }
}

extern "C" void kernel_launch(void* const* d_in, const int* in_sizes, int n_in,
                              void* d_out, int out_size, void* d_ws, size_t ws_size,
                              hipStream_t stream) {
    const float* x   = (const float*)d_in[0];
    const float* q1  = (const float*)d_in[1];
    const float* q2  = (const float*)d_in[2];
    const float* w1  = (const float*)d_in[3];
    const float* b1  = (const float*)d_in[4];
    const float* w2  = (const float*)d_in[5];
    const float* b2  = (const float*)d_in[6];
    const float* wsk = (const float*)d_in[7];
    const float* bsk = (const float*)d_in[8];
    const float* s1  = (const float*)d_in[9];
    const float* bb1 = (const float*)d_in[10];
    const float* m1  = (const float*)d_in[11];
    const float* v1  = (const float*)d_in[12];
    const float* s2  = (const float*)d_in[13];
    const float* bb2 = (const float*)d_in[14];
    const float* m2  = (const float*)d_in[15];
    const float* v2  = (const float*)d_in[16];
    float* out = (float*)d_out;

    size_t needA2 = (size_t)BS * KA2 * sizeof(__hip_bfloat16);
    size_t needW  = ((size_t)1024 * 1024 + (size_t)512 * 3072) * sizeof(__hip_bfloat16);
    char* base;
    if (ws_size >= needA2 + needW)
        base = (char*)d_ws;
    else
        base = (char*)d_in[2] + (size_t)BS * MID * sizeof(float);
    __hip_bfloat16* A2  = (__hip_bfloat16*)base;
    __hip_bfloat16* w1p = (__hip_bfloat16*)(base + needA2);
    __hip_bfloat16* w2p = w1p + 1024 * 1024;

    prep_all_kernel<<<dim3((int)(T_ALL / 256)), dim3(256), 0, stream>>>(
        x, q1, q2, w1, w2, wsk, A2, w1p, w2p);

    // gemm1: M=16384, N=1024, K=1024; h1 -> A2[:,1024:2048]  (8-phase 256^2)
    gemm1_8ph<<<dim3(256), dim3(512), 0, stream>>>(
        A2 + 2048, w1p, b1, s1, bb1, m1, v1, A2 + 1024);

    // gemm2: M=16384, N=512, K=3072 (w2 + skip folded); out fp32
    // (2-phase/tile, 3-deep A pipeline, 2-tiles-ahead staging)
    gemm2_8ph<<<dim3(256), dim3(512), 0, stream>>>(
        A2, w2p, b2, bsk, s2, bb2, m2, v2, out);
}